// Round 12
// baseline (287.424 us; speedup 1.0000x reference)
//
#include <hip/hip_runtime.h>
#include <stdint.h>

// ---------------------------------------------------------------------------
// Phased SNN:
//   0) input_kernel: simulate 544 input LIFs ONCE (1 block), store spike
//      floats in padded rows Sfin[t][640] (halves at 320-stride, zero pads);
//      bit-identical fma/cmp to the per-wave recompute it replaces.
//   1) hidden raster S: 512 blocks x 256thr; wave = (column, input-half);
//      s_in loaded via 4-deep named prefetch ring (static regs, no copies);
//      tr_in rebuilt with fmaxf. 1 barrier/step, 2 waves/SIMD.
//   2) pack S bits + zero tail rows of Sf
//   3+5 merged) gram (G = S S^T popcount) || gemm (A_T = (S@w2_0)^T, K-split)
//   4) M_T via wave-parallel decay scans
//   6) output LIF: 1 col/wave, 4 waves/block; so-history in a register;
//      static-bound unrolled GEMV; cooperative tile staging.
// Valid because w2 is never clipped -> its evolution is linear in spikes.
// ---------------------------------------------------------------------------

#define DECAY_V  0.90483741803595952f   // exp(-1/10)
#define DECAY_TR 0.95122942450071403f   // exp(-1/20)
#define REST_F   (-70.0f)
#define RESET_F  (-65.0f)
#define THRESH_F (-55.0f)
#define ALPHA_F  (0.95f)
#define BETA_F   (0.8f)
#define NU1_PRE_F  (0.001f)
#define NU1_POST_F (0.01f)
#define NU2_F      (0.0001f)
#define GAIN_F     (20.0f)
#define LOG2D    (-0.072134752044448170f)  // log2(exp(-1/20))

static constexpr int IN_D  = 544;
static constexpr int HID_D = 1024;
static constexpr int OUT_D = 2048;
static constexpr int TMAX  = 512;
static constexpr int SROW  = 640;   // padded Sfin row: 2 halves @ 320 stride

#define DP1  0.95122942450071403f
#define DP2  0.90483741803595957f
#define DP4  0.81873075307798186f
#define DP8  0.67032004603563930f
#define DP16 0.44932896411722159f
#define DP32 0.20189651799465541f

__device__ __forceinline__ float rdlane(float x, int l) {
    return __builtin_bit_cast(float,
        __builtin_amdgcn_readlane(__builtin_bit_cast(int, x), l));
}

template <int CTRL>
__device__ __forceinline__ float dpp_add(float x) {
    int y = __builtin_amdgcn_update_dpp(0, __builtin_bit_cast(int, x),
                                        CTRL, 0xF, 0xF, true);
    return x + __builtin_bit_cast(float, y);
}

__device__ __forceinline__ float wave_sum64(float x) {
    x = dpp_add<0xB1>(x);   // quad_perm [1,0,3,2]
    x = dpp_add<0x4E>(x);   // quad_perm [2,3,0,1]
    x = dpp_add<0x114>(x);  // row_shr:4
    x = dpp_add<0x118>(x);  // row_shr:8
    x = dpp_add<0x142>(x);  // row_bcast:15
    x = dpp_add<0x143>(x);  // row_bcast:31
    return rdlane(x, 63);
}

// ------------- Phase 0: input LIF once, padded spike-float rows ------------
__global__ __launch_bounds__(640)
void input_kernel(const float* __restrict__ x, const int* __restrict__ Tp,
                  float* __restrict__ Sfin)
{
    const int tid = threadIdx.x;
    const int T = Tp[0];
    const bool real = (tid < IN_D);
    // slots: [0,272) half0 | [272,320) pad0 | [320,592) half1 | [592,640) pad1
    const int slot = (tid < 272) ? tid
                   : real        ? tid + 48
                   : (tid < 592) ? tid - 272
                                 : tid;
    const float cadd = REST_F * (1.0f - DECAY_V) +
                       (real ? x[tid] * GAIN_F : -1000.0f);
    float v = REST_F;
    for (int t = 0; t < T; ++t) {
        const float vv = fmaf(DECAY_V, v, cadd);   // exact same fma as before
        const bool sp = (vv >= THRESH_F);
        v = sp ? RESET_F : vv;
        Sfin[(size_t)t * SROW + slot] = (real && sp) ? 1.f : 0.f;
    }
}

// -------- Phase 1: hidden raster, wave = (column, input-half) --------------
__global__ __launch_bounds__(256, 2)
void hidden_kernel(const float* __restrict__ Sfin, const float* __restrict__ w1,
                   const int* __restrict__ Tp, float* __restrict__ Sf)
{
    const int T = Tp[0];
    const int tid = threadIdx.x, lane = tid & 63, wv = tid >> 6;
    const int cp = wv >> 1;                  // 0/1 -> column within block
    const int h  = wv & 1;                   // input half
    const int col = blockIdx.x * 2 + cp;
    __shared__ float part[2][4];             // [parity][wave]

    float w[5], tr[5];
    #pragma unroll
    for (int k = 0; k < 5; ++k) {
        const int o = 64 * k + lane;
        w[k]  = (o < 272) ? w1[(size_t)(272 * h + o) * HID_D + col] : 0.f;
        tr[k] = 0.f;
    }
    float v_h = 0.f, b_h = 0.f, tr_h = 0.f;  // duplicated across the 2 waves
    const bool writer = (h == 0 && lane == 0);
    const float* __restrict__ sbase = Sfin + 320 * h + lane;

    // 4-deep prefetch ring, named buffers -> static registers
    float s0[5], s1[5], s2[5], s3[5];
    auto ld = [&](float (&d)[5], int trow) {
        const int tc = (trow < TMAX) ? trow : TMAX - 1;  // clamp (unused rows)
        const float* p = sbase + (size_t)tc * SROW;
        #pragma unroll
        for (int k = 0; k < 5; ++k) d[k] = p[64 * k];    // pads are zeros
    };
    auto step = [&](int t, int par, float (&s)[5]) {
        float acc = 0.f;
        #pragma unroll
        for (int k = 0; k < 5; ++k) {
            tr[k] = fmaxf(tr[k] * DECAY_TR, s[k]);   // == sp?1:tr*d (tr<=1)
            acc   = fmaf(s[k], w[k], acc);
        }
        const float p = wave_sum64(acc);
        if (lane == 0) part[par][wv] = p;
        __syncthreads();
        const float tot = p + part[par][wv ^ 1];     // commutative -> bitexact
        const float vh2 = fmaf(ALPHA_F, v_h, tot);
        const bool hp = (vh2 >= 1.0f + b_h);
        const float sh = hp ? 1.f : 0.f;
        v_h  = hp ? 0.f : vh2;
        b_h  = fmaf(BETA_F, b_h, sh);
        tr_h = hp ? 1.f : tr_h * DECAY_TR;
        const float apot = hp ? NU1_POST_F : 0.f;
        const float adep = NU1_PRE_F * tr_h;
        #pragma unroll
        for (int k = 0; k < 5; ++k) {
            const float a  = fmaf(apot, tr[k], w[k]);
            const float nw = fmaf(-adep, s[k], a);
            w[k] = __builtin_amdgcn_fmed3f(nw, 0.f, 1.f);
        }
        if (writer) Sf[(size_t)t * HID_D + col] = sh;
    };

    ld(s0, 0); ld(s1, 1); ld(s2, 2); ld(s3, 3);
    int t = 0;
    for (; t + 3 < T; t += 4) {
        step(t,     0, s0); ld(s0, t + 4);
        step(t + 1, 1, s1); ld(s1, t + 5);
        step(t + 2, 0, s2); ld(s2, t + 6);
        step(t + 3, 1, s3); ld(s3, t + 7);
    }
    if (t < T)     step(t,     0, s0);
    if (t + 1 < T) step(t + 1, 1, s1);
    if (t + 2 < T) step(t + 2, 0, s2);
}

// ---------------- Phase 2: bit-pack S (+ zero tail rows) -------------------
__global__ void pack_kernel(float* __restrict__ Sf, const int* __restrict__ Tp,
                            unsigned long long* __restrict__ Sb)
{
    const int T = Tp[0];
    const int t = blockIdx.x;
    const int lane = threadIdx.x & 63, wv = threadIdx.x >> 6;
    if (t >= T) {
        ((float4*)(Sf + (size_t)t * HID_D))[threadIdx.x] = make_float4(0.f, 0.f, 0.f, 0.f);
        return;
    }
    #pragma unroll
    for (int q = 0; q < 4; ++q) {
        const int word = wv * 4 + q;
        const float s = Sf[(size_t)t * HID_D + word * 64 + lane];
        const unsigned long long m = __ballot(s > 0.5f);
        if (lane == 0) Sb[(size_t)t * 16 + word] = m;
    }
}

// -------- Phases 3+5 merged: gram (blocks 0..1023) | gemm (rest) -----------
__global__ __launch_bounds__(256)
void gramgemm_kernel(const unsigned long long* __restrict__ Sb,
                     const int* __restrict__ Tp, float* __restrict__ G,
                     const float* __restrict__ Sf, const float* __restrict__ w2,
                     float* __restrict__ AT, int klen)
{
    __shared__ __align__(16) char smem[16640];
    const int b = blockIdx.x, tid = threadIdx.x;
    if (b < 1024) {
        const int by = b >> 5, bx = b & 31;
        if (bx > by) return;
        const int T = Tp[0];
        typedef unsigned long long u64;
        u64 (*tR)[17] = (u64(*)[17])(smem);
        u64 (*uR)[17] = (u64(*)[17])(smem + 2176);
        {
            const int r = tid >> 4, w0 = tid & 15;
            const int trow = by * 16 + r, urow = bx * 16 + r;
            tR[r][w0] = (trow < T) ? Sb[(size_t)trow * 16 + w0] : 0ULL;
            uR[r][w0] = (urow < T) ? Sb[(size_t)urow * 16 + w0] : 0ULL;
        }
        __syncthreads();
        const int tx = tid & 15, ty = tid >> 4;
        const int t = by * 16 + ty, u = bx * 16 + tx;
        if (t < T && u < t) {
            int s = 0;
            #pragma unroll
            for (int w0 = 0; w0 < 16; ++w0) s += __popcll(tR[ty][w0] & uR[tx][w0]);
            G[(size_t)t * TMAX + u] = (float)s;
        }
    } else {
        const int g = b - 1024;
        const int z = g >> 7, r = g & 127;
        const int j0 = (r & 15) * 128, t0 = (r >> 4) * 64;
        const int kbase = z * klen;
        float (*Ss)[68]  = (float(*)[68])(smem);
        float (*Ws)[192] = (float(*)[192])(smem + 4352);
        const int sr = tid >> 2, sq = tid & 3;
        const int wq2 = tid & 31, wr2 = tid >> 5;
        const int wcol = (wq2 >> 1) * 12 + (wq2 & 1) * 4;
        const int tj = tid & 15, tt = tid >> 4;
        const int tjc = tj * 12;

        float acc[4][8];
        #pragma unroll
        for (int a = 0; a < 4; ++a)
            #pragma unroll
            for (int bb = 0; bb < 8; ++bb) acc[a][bb] = 0.f;

        for (int k0 = 0; k0 < klen; k0 += 16) {
            const float4 sv = *(const float4*)&Sf[(size_t)(t0 + sr) * HID_D + kbase + k0 + sq * 4];
            const float4 wa = *(const float4*)&w2[(size_t)(kbase + k0 + wr2) * OUT_D + j0 + wq2 * 4];
            const float4 wb = *(const float4*)&w2[(size_t)(kbase + k0 + wr2 + 8) * OUT_D + j0 + wq2 * 4];
            __syncthreads();
            Ss[sq * 4 + 0][sr] = sv.x;
            Ss[sq * 4 + 1][sr] = sv.y;
            Ss[sq * 4 + 2][sr] = sv.z;
            Ss[sq * 4 + 3][sr] = sv.w;
            *(float4*)&Ws[wr2][wcol] = wa;
            *(float4*)&Ws[wr2 + 8][wcol] = wb;
            __syncthreads();
            #pragma unroll
            for (int kk = 0; kk < 16; ++kk) {
                const float4 a4 = *(const float4*)&Ss[kk][tt * 4];
                const float4 b0 = *(const float4*)&Ws[kk][tjc];
                const float4 b1 = *(const float4*)&Ws[kk][tjc + 4];
                const float aa[4] = {a4.x, a4.y, a4.z, a4.w};
                const float bbv[8] = {b0.x, b0.y, b0.z, b0.w, b1.x, b1.y, b1.z, b1.w};
                #pragma unroll
                for (int ti = 0; ti < 4; ++ti)
                    #pragma unroll
                    for (int jj = 0; jj < 8; ++jj)
                        acc[ti][jj] = fmaf(aa[ti], bbv[jj], acc[ti][jj]);
            }
        }
        #pragma unroll
        for (int jj = 0; jj < 8; ++jj)
            *(float4*)&AT[(size_t)z * OUT_D * TMAX +
                          (size_t)(j0 + tj * 8 + jj) * TMAX + t0 + tt * 4] =
                make_float4(acc[0][jj], acc[1][jj], acc[2][jj], acc[3][jj]);
    }
}

// -------------- Phase 4: M_T columns via parallel decay scans --------------
__global__ __launch_bounds__(256)
void mt_kernel(const float* __restrict__ G, const int* __restrict__ Tp,
               float* __restrict__ MT)
{
    const int T = Tp[0];
    const int lane = threadIdx.x & 63;
    const int t = blockIdx.x * 4 + (threadIdx.x >> 6);
    if (t >= T) return;
    const float* Gr = G + (size_t)t * TMAX;
    const float dl1  = exp2f((float)(lane + 1) * LOG2D);
    const float d64l = exp2f((float)(64 - lane) * LOG2D);

    float g[8], kk[8];
    #pragma unroll
    for (int c = 0; c < 8; ++c) {
        const int tau = 64 * c + lane;
        g[c] = (tau < t) ? Gr[tau] : 0.f;
    }
    float kc = 0.f;
    #pragma unroll
    for (int c = 7; c >= 0; --c) {
        float k = g[c], u;
        u = __shfl_down(k, 1, 64);  if (lane < 63) k = fmaf(DP1, u, k);
        u = __shfl_down(k, 2, 64);  if (lane < 62) k = fmaf(DP2, u, k);
        u = __shfl_down(k, 4, 64);  if (lane < 60) k = fmaf(DP4, u, k);
        u = __shfl_down(k, 8, 64);  if (lane < 56) k = fmaf(DP8, u, k);
        u = __shfl_down(k, 16, 64); if (lane < 48) k = fmaf(DP16, u, k);
        u = __shfl_down(k, 32, 64); if (lane < 32) k = fmaf(DP32, u, k);
        k = fmaf(d64l, kc, k);
        kk[c] = k;
        kc = rdlane(k, 0);
    }
    float hc = 0.f;
    #pragma unroll
    for (int c = 0; c < 8; ++c) {
        float h = g[c], u;
        u = __shfl_up(h, 1, 64);  if (lane >= 1)  h = fmaf(DP1, u, h);
        u = __shfl_up(h, 2, 64);  if (lane >= 2)  h = fmaf(DP2, u, h);
        u = __shfl_up(h, 4, 64);  if (lane >= 4)  h = fmaf(DP4, u, h);
        u = __shfl_up(h, 8, 64);  if (lane >= 8)  h = fmaf(DP8, u, h);
        u = __shfl_up(h, 16, 64); if (lane >= 16) h = fmaf(DP16, u, h);
        u = __shfl_up(h, 32, 64); if (lane >= 32) h = fmaf(DP32, u, h);
        h = fmaf(dl1, hc, h);
        const int tau = 64 * c + lane;
        if (tau < t) MT[(size_t)tau * TMAX + t] = NU2_F * (h - kk[c]);
        hc = rdlane(h, 63);
    }
}

// ------- Phase 6: output recurrence, 1 col/wave, 4 waves/block -------------
template <int C>
__device__ __forceinline__ void out_chunk(
    const float* __restrict__ AT, const float* __restrict__ MT,
    float (&hs)[8], float& v, float* __restrict__ out,
    int j, int lane, int w, int T, int nparts, float* __restrict__ LD)
{
    __syncthreads();   // prev chunk's tile reads done; this chunk's tile ready
    constexpr int t0 = 64 * C;
    const int rem = T - t0;
    const int mtv = (rem < 64) ? rem : 64;
    float av = AT[(size_t)j * TMAX + t0 + lane];
    #pragma unroll
    for (int p = 1; p < 4; ++p)                 // ascending p: fixed sum order
        if (p < nparts)
            av += AT[(size_t)p * OUT_D * TMAX + (size_t)j * TMAX + t0 + lane];
    const bool hasNext = (C + 1 < 8) && (64 * (C + 1) < T);
    if (hasNext) {   // stage NEXT chunk's diagonal tile early (16 rows/wave)
        float* dst = LD + ((C + 1) & 1) * 4096;
        const float* src = MT + (size_t)(64 * (C + 1)) * TMAX + 64 * (C + 1) + lane;
        #pragma unroll
        for (int rr = 0; rr < 16; ++rr) {
            const int r = w * 16 + rr;
            const float vv = src[(size_t)r * TMAX];
            dst[r * 64 + lane] = (r < lane) ? vv : 0.f;      // tau<t mask
        }
    }
    const float* ldb = LD + (C & 1) * 4096;
    const float cc = REST_F * (1.0f - DECAY_V);
    float acc = hs[C];
    float sreg = 0.f;   // lane tt keeps so(t0+tt)

    auto sstep = [&](int tt, float& m, int reload) {
        const float iv = rdlane(av + acc, tt);
        const float vd = fmaf(DECAY_V, v, cc) + iv;
        const bool sp = (vd >= THRESH_F);
        const float so = sp ? 1.f : 0.f;        // wave-uniform
        v = sp ? RESET_F : vd;
        sreg = (lane == tt) ? so : sreg;
        acc = fmaf(so, m, acc);
        if (reload < 64) m = ldb[reload * 64 + lane];
    };

    if (rem >= 64) {                            // static path, 4-deep LDS ring
        float m0 = ldb[lane], m1 = ldb[64 + lane],
              m2 = ldb[128 + lane], m3 = ldb[192 + lane];
        #pragma unroll 1
        for (int tt = 0; tt < 64; tt += 4) {
            sstep(tt,     m0, tt + 4);
            sstep(tt + 1, m1, tt + 5);
            sstep(tt + 2, m2, tt + 6);
            sstep(tt + 3, m3, tt + 7);
        }
    } else {                                    // tail chunk, dynamic bound
        float m0 = ldb[lane];
        float m1 = (mtv > 1) ? ldb[64 + lane] : 0.f;
        for (int tt = 0; tt < mtv; ++tt) {
            const float mv = m0;
            m0 = m1;
            if (tt + 2 < mtv) m1 = ldb[(tt + 2) * 64 + lane];
            const float iv = rdlane(av + acc, tt);
            const float vd = fmaf(DECAY_V, v, cc) + iv;
            const bool sp = (vd >= THRESH_F);
            const float so = sp ? 1.f : 0.f;
            v = sp ? RESET_F : vd;
            sreg = (lane == tt) ? so : sreg;
            acc = fmaf(so, mv, acc);
        }
    }
    if (lane < mtv) out[(size_t)(t0 + lane) * OUT_D + j] = sreg;

    if (hasNext) {   // batched scatter into future chunks (ascending tt per K)
        #pragma unroll 4
        for (int tt = 0; tt < 64; ++tt) {
            const float s = rdlane(sreg, tt);
            const float* Mrow = MT + (size_t)(t0 + tt) * TMAX + lane;
            #pragma unroll
            for (int K = C + 1; K < 8; ++K)
                hs[K] = fmaf(s, Mrow[64 * K], hs[K]);
        }
    }
}

__global__ __launch_bounds__(256, 2)
void out_kernel(const float* __restrict__ AT, const float* __restrict__ MT,
                const int* __restrict__ Tp, float* __restrict__ out, int nparts)
{
    const int T = Tp[0];
    const int tid = threadIdx.x, lane = tid & 63, w = tid >> 6;
    const int j = blockIdx.x * 4 + w;           // 512 blocks, 1 col per wave
    __shared__ float LD[2 * 4096];

    float hs[8];
    #pragma unroll
    for (int k = 0; k < 8; ++k) hs[k] = 0.f;
    float v = REST_F;

    {   // stage chunk 0 tile (cooperative)
        const float* src = MT + lane;
        #pragma unroll
        for (int rr = 0; rr < 16; ++rr) {
            const int r = w * 16 + rr;
            const float vv = src[(size_t)r * TMAX];
            LD[r * 64 + lane] = (r < lane) ? vv : 0.f;
        }
    }
    out_chunk<0>(AT, MT, hs, v, out, j, lane, w, T, nparts, LD);
    if (T >  64) out_chunk<1>(AT, MT, hs, v, out, j, lane, w, T, nparts, LD);
    if (T > 128) out_chunk<2>(AT, MT, hs, v, out, j, lane, w, T, nparts, LD);
    if (T > 192) out_chunk<3>(AT, MT, hs, v, out, j, lane, w, T, nparts, LD);
    if (T > 256) out_chunk<4>(AT, MT, hs, v, out, j, lane, w, T, nparts, LD);
    if (T > 320) out_chunk<5>(AT, MT, hs, v, out, j, lane, w, T, nparts, LD);
    if (T > 384) out_chunk<6>(AT, MT, hs, v, out, j, lane, w, T, nparts, LD);
    if (T > 448) out_chunk<7>(AT, MT, hs, v, out, j, lane, w, T, nparts, LD);
}

extern "C" void kernel_launch(void* const* d_in, const int* in_sizes, int n_in,
                              void* d_out, int out_size, void* d_ws, size_t ws_size,
                              hipStream_t stream) {
    const float* x  = (const float*)d_in[0];
    const float* w1 = (const float*)d_in[1];
    const float* w2 = (const float*)d_in[2];
    const int*   Tp = (const int*)d_in[3];
    float* out = (float*)d_out;
    char* ws = (char*)d_ws;
    // layout: Sfin 1.25M | Sb 64K | G 1M | MT 1M | Sf 2M | AT nparts*4M
    float* Sfin = (float*)(ws);
    unsigned long long* Sb = (unsigned long long*)(ws + 1310720);
    float* G  = (float*)(ws + 1310720 + 65536);
    float* MT = (float*)(ws + 1310720 + 65536 + 1048576);
    float* Sf = (float*)(ws + 1310720 + 65536 + 2 * 1048576);
    float* AT = (float*)(ws + 1310720 + 65536 + 2 * 1048576 + 2097152);
    const size_t base = 1310720 + 65536 + 2 * 1048576 + 2097152;
    const int nparts = (ws_size >= base + 4 * 4194304) ? 4
                     : (ws_size >= base + 2 * 4194304) ? 2 : 1;
    const int klen = 1024 / nparts;

    hipLaunchKernelGGL(input_kernel,  dim3(1), dim3(640), 0, stream, x, Tp, Sfin);
    hipLaunchKernelGGL(hidden_kernel, dim3(HID_D / 2), dim3(256), 0, stream, Sfin, w1, Tp, Sf);
    hipLaunchKernelGGL(pack_kernel,   dim3(TMAX), dim3(256), 0, stream, Sf, Tp, Sb);
    hipLaunchKernelGGL(gramgemm_kernel, dim3(1024 + 128 * nparts), dim3(256), 0, stream,
                       Sb, Tp, G, Sf, w2, AT, klen);
    hipLaunchKernelGGL(mt_kernel,     dim3(128), dim3(256), 0, stream, G, Tp, MT);
    hipLaunchKernelGGL(out_kernel,    dim3(OUT_D / 4), dim3(256), 0, stream, AT, MT, Tp, out, nparts);
}

// Round 13
// 287.125 us; speedup vs baseline: 1.0010x; 1.0010x over previous
//
#include <hip/hip_runtime.h>
#include <stdint.h>

// ---------------------------------------------------------------------------
// Phased SNN:
//   0) input_kernel: simulate 544 input LIFs ONCE (1 block), store spike
//      floats in padded rows Sfin[t][640] (halves at 320-stride, zero pads);
//      bit-identical fma/cmp to the per-wave recompute it replaces.
//   1) hidden raster S: 512 blocks x 256thr; wave = (column, input-half);
//      s_in loaded via 4-deep named prefetch ring (static regs, no copies);
//      tr_in rebuilt with fmaxf. 1 barrier/step, 2 waves/SIMD.
//   2) pack S bits + zero tail rows of Sf
//   3+5 merged) gram (G = S S^T popcount) || gemm (A_T = (S@w2_0)^T, K-split)
//   4) M_T via wave-parallel decay scans
//   6) output LIF: 1 col/wave, 4 waves/block; so-history in a register;
//      static-bound unrolled GEMV; cooperative tile staging.
// Valid because w2 is never clipped -> its evolution is linear in spikes.
// ---------------------------------------------------------------------------

#define DECAY_V  0.90483741803595952f   // exp(-1/10)
#define DECAY_TR 0.95122942450071403f   // exp(-1/20)
#define REST_F   (-70.0f)
#define RESET_F  (-65.0f)
#define THRESH_F (-55.0f)
#define ALPHA_F  (0.95f)
#define BETA_F   (0.8f)
#define NU1_PRE_F  (0.001f)
#define NU1_POST_F (0.01f)
#define NU2_F      (0.0001f)
#define GAIN_F     (20.0f)
#define LOG2D    (-0.072134752044448170f)  // log2(exp(-1/20))

static constexpr int IN_D  = 544;
static constexpr int HID_D = 1024;
static constexpr int OUT_D = 2048;
static constexpr int TMAX  = 512;
static constexpr int SROW  = 640;   // padded Sfin row: 2 halves @ 320 stride

#define DP1  0.95122942450071403f
#define DP2  0.90483741803595957f
#define DP4  0.81873075307798186f
#define DP8  0.67032004603563930f
#define DP16 0.44932896411722159f
#define DP32 0.20189651799465541f

__device__ __forceinline__ float rdlane(float x, int l) {
    return __builtin_bit_cast(float,
        __builtin_amdgcn_readlane(__builtin_bit_cast(int, x), l));
}

template <int CTRL>
__device__ __forceinline__ float dpp_add(float x) {
    int y = __builtin_amdgcn_update_dpp(0, __builtin_bit_cast(int, x),
                                        CTRL, 0xF, 0xF, true);
    return x + __builtin_bit_cast(float, y);
}

__device__ __forceinline__ float wave_sum64(float x) {
    x = dpp_add<0xB1>(x);   // quad_perm [1,0,3,2]
    x = dpp_add<0x4E>(x);   // quad_perm [2,3,0,1]
    x = dpp_add<0x114>(x);  // row_shr:4
    x = dpp_add<0x118>(x);  // row_shr:8
    x = dpp_add<0x142>(x);  // row_bcast:15
    x = dpp_add<0x143>(x);  // row_bcast:31
    return rdlane(x, 63);
}

// ------------- Phase 0: input LIF once, padded spike-float rows ------------
__global__ __launch_bounds__(640)
void input_kernel(const float* __restrict__ x, const int* __restrict__ Tp,
                  float* __restrict__ Sfin)
{
    const int tid = threadIdx.x;
    const int T = Tp[0];
    const bool real = (tid < IN_D);
    // slots: [0,272) half0 | [272,320) pad0 | [320,592) half1 | [592,640) pad1
    const int slot = (tid < 272) ? tid
                   : real        ? tid + 48
                   : (tid < 592) ? tid - 272
                                 : tid;
    const float cadd = REST_F * (1.0f - DECAY_V) +
                       (real ? x[tid] * GAIN_F : -1000.0f);
    float v = REST_F;
    for (int t = 0; t < T; ++t) {
        const float vv = fmaf(DECAY_V, v, cadd);   // exact same fma as before
        const bool sp = (vv >= THRESH_F);
        v = sp ? RESET_F : vv;
        Sfin[(size_t)t * SROW + slot] = (real && sp) ? 1.f : 0.f;
    }
}

// -------- Phase 1: hidden raster, wave = (column, input-half) --------------
__global__ __launch_bounds__(256, 2)
void hidden_kernel(const float* __restrict__ Sfin, const float* __restrict__ w1,
                   const int* __restrict__ Tp, float* __restrict__ Sf)
{
    const int T = Tp[0];
    const int tid = threadIdx.x, lane = tid & 63, wv = tid >> 6;
    const int cp = wv >> 1;                  // 0/1 -> column within block
    const int h  = wv & 1;                   // input half
    const int col = blockIdx.x * 2 + cp;
    __shared__ float part[2][4];             // [parity][wave]

    float w[5], tr[5];
    #pragma unroll
    for (int k = 0; k < 5; ++k) {
        const int o = 64 * k + lane;
        w[k]  = (o < 272) ? w1[(size_t)(272 * h + o) * HID_D + col] : 0.f;
        tr[k] = 0.f;
    }
    float v_h = 0.f, b_h = 0.f, tr_h = 0.f;  // duplicated across the 2 waves
    const bool writer = (h == 0 && lane == 0);
    const float* __restrict__ sbase = Sfin + 320 * h + lane;

    // 4-deep prefetch ring, named buffers -> static registers
    float s0[5], s1[5], s2[5], s3[5];
    auto ld = [&](float (&d)[5], int trow) {
        const int tc = (trow < TMAX) ? trow : TMAX - 1;  // clamp (unused rows)
        const float* p = sbase + (size_t)tc * SROW;
        #pragma unroll
        for (int k = 0; k < 5; ++k) d[k] = p[64 * k];    // pads are zeros
    };
    auto step = [&](int t, int par, float (&s)[5]) {
        float acc = 0.f;
        #pragma unroll
        for (int k = 0; k < 5; ++k) {
            tr[k] = fmaxf(tr[k] * DECAY_TR, s[k]);   // == sp?1:tr*d (tr<=1)
            acc   = fmaf(s[k], w[k], acc);
        }
        const float p = wave_sum64(acc);
        if (lane == 0) part[par][wv] = p;
        __syncthreads();
        const float tot = p + part[par][wv ^ 1];     // commutative -> bitexact
        const float vh2 = fmaf(ALPHA_F, v_h, tot);
        const bool hp = (vh2 >= 1.0f + b_h);
        const float sh = hp ? 1.f : 0.f;
        v_h  = hp ? 0.f : vh2;
        b_h  = fmaf(BETA_F, b_h, sh);
        tr_h = hp ? 1.f : tr_h * DECAY_TR;
        const float apot = hp ? NU1_POST_F : 0.f;
        const float adep = NU1_PRE_F * tr_h;
        #pragma unroll
        for (int k = 0; k < 5; ++k) {
            const float a  = fmaf(apot, tr[k], w[k]);
            const float nw = fmaf(-adep, s[k], a);
            w[k] = __builtin_amdgcn_fmed3f(nw, 0.f, 1.f);
        }
        if (writer) Sf[(size_t)t * HID_D + col] = sh;
    };

    ld(s0, 0); ld(s1, 1); ld(s2, 2); ld(s3, 3);
    int t = 0;
    for (; t + 3 < T; t += 4) {
        step(t,     0, s0); ld(s0, t + 4);
        step(t + 1, 1, s1); ld(s1, t + 5);
        step(t + 2, 0, s2); ld(s2, t + 6);
        step(t + 3, 1, s3); ld(s3, t + 7);
    }
    if (t < T)     step(t,     0, s0);
    if (t + 1 < T) step(t + 1, 1, s1);
    if (t + 2 < T) step(t + 2, 0, s2);
}

// ---------------- Phase 2: bit-pack S (+ zero tail rows) -------------------
__global__ void pack_kernel(float* __restrict__ Sf, const int* __restrict__ Tp,
                            unsigned long long* __restrict__ Sb)
{
    const int T = Tp[0];
    const int t = blockIdx.x;
    const int lane = threadIdx.x & 63, wv = threadIdx.x >> 6;
    if (t >= T) {
        ((float4*)(Sf + (size_t)t * HID_D))[threadIdx.x] = make_float4(0.f, 0.f, 0.f, 0.f);
        return;
    }
    #pragma unroll
    for (int q = 0; q < 4; ++q) {
        const int word = wv * 4 + q;
        const float s = Sf[(size_t)t * HID_D + word * 64 + lane];
        const unsigned long long m = __ballot(s > 0.5f);
        if (lane == 0) Sb[(size_t)t * 16 + word] = m;
    }
}

// -------- Phases 3+5 merged: gram (blocks 0..1023) | gemm (rest) -----------
__global__ __launch_bounds__(256)
void gramgemm_kernel(const unsigned long long* __restrict__ Sb,
                     const int* __restrict__ Tp, float* __restrict__ G,
                     const float* __restrict__ Sf, const float* __restrict__ w2,
                     float* __restrict__ AT, int klen)
{
    __shared__ __align__(16) char smem[16640];
    const int b = blockIdx.x, tid = threadIdx.x;
    if (b < 1024) {
        const int by = b >> 5, bx = b & 31;
        if (bx > by) return;
        const int T = Tp[0];
        typedef unsigned long long u64;
        u64 (*tR)[17] = (u64(*)[17])(smem);
        u64 (*uR)[17] = (u64(*)[17])(smem + 2176);
        {
            const int r = tid >> 4, w0 = tid & 15;
            const int trow = by * 16 + r, urow = bx * 16 + r;
            tR[r][w0] = (trow < T) ? Sb[(size_t)trow * 16 + w0] : 0ULL;
            uR[r][w0] = (urow < T) ? Sb[(size_t)urow * 16 + w0] : 0ULL;
        }
        __syncthreads();
        const int tx = tid & 15, ty = tid >> 4;
        const int t = by * 16 + ty, u = bx * 16 + tx;
        if (t < T && u < t) {
            int s = 0;
            #pragma unroll
            for (int w0 = 0; w0 < 16; ++w0) s += __popcll(tR[ty][w0] & uR[tx][w0]);
            G[(size_t)t * TMAX + u] = (float)s;
        }
    } else {
        const int g = b - 1024;
        const int z = g >> 7, r = g & 127;
        const int j0 = (r & 15) * 128, t0 = (r >> 4) * 64;
        const int kbase = z * klen;
        float (*Ss)[68]  = (float(*)[68])(smem);
        float (*Ws)[192] = (float(*)[192])(smem + 4352);
        const int sr = tid >> 2, sq = tid & 3;
        const int wq2 = tid & 31, wr2 = tid >> 5;
        const int wcol = (wq2 >> 1) * 12 + (wq2 & 1) * 4;
        const int tj = tid & 15, tt = tid >> 4;
        const int tjc = tj * 12;

        float acc[4][8];
        #pragma unroll
        for (int a = 0; a < 4; ++a)
            #pragma unroll
            for (int bb = 0; bb < 8; ++bb) acc[a][bb] = 0.f;

        for (int k0 = 0; k0 < klen; k0 += 16) {
            const float4 sv = *(const float4*)&Sf[(size_t)(t0 + sr) * HID_D + kbase + k0 + sq * 4];
            const float4 wa = *(const float4*)&w2[(size_t)(kbase + k0 + wr2) * OUT_D + j0 + wq2 * 4];
            const float4 wb = *(const float4*)&w2[(size_t)(kbase + k0 + wr2 + 8) * OUT_D + j0 + wq2 * 4];
            __syncthreads();
            Ss[sq * 4 + 0][sr] = sv.x;
            Ss[sq * 4 + 1][sr] = sv.y;
            Ss[sq * 4 + 2][sr] = sv.z;
            Ss[sq * 4 + 3][sr] = sv.w;
            *(float4*)&Ws[wr2][wcol] = wa;
            *(float4*)&Ws[wr2 + 8][wcol] = wb;
            __syncthreads();
            #pragma unroll
            for (int kk = 0; kk < 16; ++kk) {
                const float4 a4 = *(const float4*)&Ss[kk][tt * 4];
                const float4 b0 = *(const float4*)&Ws[kk][tjc];
                const float4 b1 = *(const float4*)&Ws[kk][tjc + 4];
                const float aa[4] = {a4.x, a4.y, a4.z, a4.w};
                const float bbv[8] = {b0.x, b0.y, b0.z, b0.w, b1.x, b1.y, b1.z, b1.w};
                #pragma unroll
                for (int ti = 0; ti < 4; ++ti)
                    #pragma unroll
                    for (int jj = 0; jj < 8; ++jj)
                        acc[ti][jj] = fmaf(aa[ti], bbv[jj], acc[ti][jj]);
            }
        }
        #pragma unroll
        for (int jj = 0; jj < 8; ++jj)
            *(float4*)&AT[(size_t)z * OUT_D * TMAX +
                          (size_t)(j0 + tj * 8 + jj) * TMAX + t0 + tt * 4] =
                make_float4(acc[0][jj], acc[1][jj], acc[2][jj], acc[3][jj]);
    }
}

// -------------- Phase 4: M_T columns via parallel decay scans --------------
__global__ __launch_bounds__(256)
void mt_kernel(const float* __restrict__ G, const int* __restrict__ Tp,
               float* __restrict__ MT)
{
    const int T = Tp[0];
    const int lane = threadIdx.x & 63;
    const int t = blockIdx.x * 4 + (threadIdx.x >> 6);
    if (t >= T) return;
    const float* Gr = G + (size_t)t * TMAX;
    const float dl1  = exp2f((float)(lane + 1) * LOG2D);
    const float d64l = exp2f((float)(64 - lane) * LOG2D);

    float g[8], kk[8];
    #pragma unroll
    for (int c = 0; c < 8; ++c) {
        const int tau = 64 * c + lane;
        g[c] = (tau < t) ? Gr[tau] : 0.f;
    }
    float kc = 0.f;
    #pragma unroll
    for (int c = 7; c >= 0; --c) {
        float k = g[c], u;
        u = __shfl_down(k, 1, 64);  if (lane < 63) k = fmaf(DP1, u, k);
        u = __shfl_down(k, 2, 64);  if (lane < 62) k = fmaf(DP2, u, k);
        u = __shfl_down(k, 4, 64);  if (lane < 60) k = fmaf(DP4, u, k);
        u = __shfl_down(k, 8, 64);  if (lane < 56) k = fmaf(DP8, u, k);
        u = __shfl_down(k, 16, 64); if (lane < 48) k = fmaf(DP16, u, k);
        u = __shfl_down(k, 32, 64); if (lane < 32) k = fmaf(DP32, u, k);
        k = fmaf(d64l, kc, k);
        kk[c] = k;
        kc = rdlane(k, 0);
    }
    float hc = 0.f;
    #pragma unroll
    for (int c = 0; c < 8; ++c) {
        float h = g[c], u;
        u = __shfl_up(h, 1, 64);  if (lane >= 1)  h = fmaf(DP1, u, h);
        u = __shfl_up(h, 2, 64);  if (lane >= 2)  h = fmaf(DP2, u, h);
        u = __shfl_up(h, 4, 64);  if (lane >= 4)  h = fmaf(DP4, u, h);
        u = __shfl_up(h, 8, 64);  if (lane >= 8)  h = fmaf(DP8, u, h);
        u = __shfl_up(h, 16, 64); if (lane >= 16) h = fmaf(DP16, u, h);
        u = __shfl_up(h, 32, 64); if (lane >= 32) h = fmaf(DP32, u, h);
        h = fmaf(dl1, hc, h);
        const int tau = 64 * c + lane;
        if (tau < t) MT[(size_t)tau * TMAX + t] = NU2_F * (h - kk[c]);
        hc = rdlane(h, 63);
    }
}

// ------- Phase 6: output recurrence, 1 col/wave, 4 waves/block -------------
template <int C>
__device__ __forceinline__ void out_chunk(
    const float* __restrict__ AT, const float* __restrict__ MT,
    float (&hs)[8], float& v, float* __restrict__ out,
    int j, int lane, int w, int T, int nparts, float* __restrict__ LD)
{
    __syncthreads();   // prev chunk's tile reads done; this chunk's tile ready
    constexpr int t0 = 64 * C;
    const int rem = T - t0;
    const int mtv = (rem < 64) ? rem : 64;
    float av = AT[(size_t)j * TMAX + t0 + lane];
    #pragma unroll
    for (int p = 1; p < 4; ++p)                 // ascending p: fixed sum order
        if (p < nparts)
            av += AT[(size_t)p * OUT_D * TMAX + (size_t)j * TMAX + t0 + lane];
    const bool hasNext = (C + 1 < 8) && (64 * (C + 1) < T);
    if (hasNext) {   // stage NEXT chunk's diagonal tile early (16 rows/wave)
        float* dst = LD + ((C + 1) & 1) * 4096;
        const float* src = MT + (size_t)(64 * (C + 1)) * TMAX + 64 * (C + 1) + lane;
        #pragma unroll
        for (int rr = 0; rr < 16; ++rr) {
            const int r = w * 16 + rr;
            const float vv = src[(size_t)r * TMAX];
            dst[r * 64 + lane] = (r < lane) ? vv : 0.f;      // tau<t mask
        }
    }
    const float* ldb = LD + (C & 1) * 4096;
    const float cc = REST_F * (1.0f - DECAY_V);
    float acc = hs[C];
    float sreg = 0.f;   // lane tt keeps so(t0+tt)

    auto sstep = [&](int tt, float& m, int reload) {
        const float iv = rdlane(av + acc, tt);
        const float vd = fmaf(DECAY_V, v, cc) + iv;
        const bool sp = (vd >= THRESH_F);
        const float so = sp ? 1.f : 0.f;        // wave-uniform
        v = sp ? RESET_F : vd;
        sreg = (lane == tt) ? so : sreg;
        acc = fmaf(so, m, acc);
        if (reload < 64) m = ldb[reload * 64 + lane];
    };

    if (rem >= 64) {                            // static path, 4-deep LDS ring
        float m0 = ldb[lane], m1 = ldb[64 + lane],
              m2 = ldb[128 + lane], m3 = ldb[192 + lane];
        #pragma unroll 1
        for (int tt = 0; tt < 64; tt += 4) {
            sstep(tt,     m0, tt + 4);
            sstep(tt + 1, m1, tt + 5);
            sstep(tt + 2, m2, tt + 6);
            sstep(tt + 3, m3, tt + 7);
        }
    } else {                                    // tail chunk, dynamic bound
        float m0 = ldb[lane];
        float m1 = (mtv > 1) ? ldb[64 + lane] : 0.f;
        for (int tt = 0; tt < mtv; ++tt) {
            const float mv = m0;
            m0 = m1;
            if (tt + 2 < mtv) m1 = ldb[(tt + 2) * 64 + lane];
            const float iv = rdlane(av + acc, tt);
            const float vd = fmaf(DECAY_V, v, cc) + iv;
            const bool sp = (vd >= THRESH_F);
            const float so = sp ? 1.f : 0.f;
            v = sp ? RESET_F : vd;
            sreg = (lane == tt) ? so : sreg;
            acc = fmaf(so, mv, acc);
        }
    }
    if (lane < mtv) out[(size_t)(t0 + lane) * OUT_D + j] = sreg;

    if (hasNext) {   // batched scatter into future chunks (ascending tt per K)
        #pragma unroll 4
        for (int tt = 0; tt < 64; ++tt) {
            const float s = rdlane(sreg, tt);
            const float* Mrow = MT + (size_t)(t0 + tt) * TMAX + lane;
            #pragma unroll
            for (int K = C + 1; K < 8; ++K)
                hs[K] = fmaf(s, Mrow[64 * K], hs[K]);
        }
    }
}

__global__ __launch_bounds__(256, 2)
void out_kernel(const float* __restrict__ AT, const float* __restrict__ MT,
                const int* __restrict__ Tp, float* __restrict__ out, int nparts)
{
    const int T = Tp[0];
    const int tid = threadIdx.x, lane = tid & 63, w = tid >> 6;
    const int j = blockIdx.x * 4 + w;           // 512 blocks, 1 col per wave
    __shared__ float LD[2 * 4096];

    float hs[8];
    #pragma unroll
    for (int k = 0; k < 8; ++k) hs[k] = 0.f;
    float v = REST_F;

    {   // stage chunk 0 tile (cooperative)
        const float* src = MT + lane;
        #pragma unroll
        for (int rr = 0; rr < 16; ++rr) {
            const int r = w * 16 + rr;
            const float vv = src[(size_t)r * TMAX];
            LD[r * 64 + lane] = (r < lane) ? vv : 0.f;
        }
    }
    out_chunk<0>(AT, MT, hs, v, out, j, lane, w, T, nparts, LD);
    if (T >  64) out_chunk<1>(AT, MT, hs, v, out, j, lane, w, T, nparts, LD);
    if (T > 128) out_chunk<2>(AT, MT, hs, v, out, j, lane, w, T, nparts, LD);
    if (T > 192) out_chunk<3>(AT, MT, hs, v, out, j, lane, w, T, nparts, LD);
    if (T > 256) out_chunk<4>(AT, MT, hs, v, out, j, lane, w, T, nparts, LD);
    if (T > 320) out_chunk<5>(AT, MT, hs, v, out, j, lane, w, T, nparts, LD);
    if (T > 384) out_chunk<6>(AT, MT, hs, v, out, j, lane, w, T, nparts, LD);
    if (T > 448) out_chunk<7>(AT, MT, hs, v, out, j, lane, w, T, nparts, LD);
}

extern "C" void kernel_launch(void* const* d_in, const int* in_sizes, int n_in,
                              void* d_out, int out_size, void* d_ws, size_t ws_size,
                              hipStream_t stream) {
    const float* x  = (const float*)d_in[0];
    const float* w1 = (const float*)d_in[1];
    const float* w2 = (const float*)d_in[2];
    const int*   Tp = (const int*)d_in[3];
    float* out = (float*)d_out;
    char* ws = (char*)d_ws;
    // layout: Sfin 1.25M | Sb 64K | G 1M | MT 1M | Sf 2M | AT nparts*4M
    float* Sfin = (float*)(ws);
    unsigned long long* Sb = (unsigned long long*)(ws + 1310720);
    float* G  = (float*)(ws + 1310720 + 65536);
    float* MT = (float*)(ws + 1310720 + 65536 + 1048576);
    float* Sf = (float*)(ws + 1310720 + 65536 + 2 * 1048576);
    float* AT = (float*)(ws + 1310720 + 65536 + 2 * 1048576 + 2097152);
    const size_t base = 1310720 + 65536 + 2 * 1048576 + 2097152;
    const int nparts = (ws_size >= base + 4 * 4194304) ? 4
                     : (ws_size >= base + 2 * 4194304) ? 2 : 1;
    const int klen = 1024 / nparts;

    hipLaunchKernelGGL(input_kernel,  dim3(1), dim3(640), 0, stream, x, Tp, Sfin);
    hipLaunchKernelGGL(hidden_kernel, dim3(HID_D / 2), dim3(256), 0, stream, Sfin, w1, Tp, Sf);
    hipLaunchKernelGGL(pack_kernel,   dim3(TMAX), dim3(256), 0, stream, Sf, Tp, Sb);
    hipLaunchKernelGGL(gramgemm_kernel, dim3(1024 + 128 * nparts), dim3(256), 0, stream,
                       Sb, Tp, G, Sf, w2, AT, klen);
    hipLaunchKernelGGL(mt_kernel,     dim3(128), dim3(256), 0, stream, G, Tp, MT);
    hipLaunchKernelGGL(out_kernel,    dim3(OUT_D / 4), dim3(256), 0, stream, AT, MT, Tp, out, nparts);
}